// Round 9
// baseline (283.558 us; speedup 1.0000x reference)
//
#include <hip/hip_runtime.h>

typedef unsigned short u16;
typedef __attribute__((ext_vector_type(8))) _Float16 f16x8;
typedef __attribute__((ext_vector_type(4))) float f32x4;
typedef __attribute__((ext_vector_type(4))) unsigned short u16x4;
typedef __attribute__((ext_vector_type(8))) unsigned short u16x8;

#define MFMA16F __builtin_amdgcn_mfma_f32_16x16x32_f16

#define HW   16384
#define NCLS 150
#define NPAD 160
#define CDIM 256

// LDS strides (shorts)
#define FT_STRIDE 264   // featT [64 px][256 c]
#define FN_STRIDE 72    // featN [256 c][64 px]
#define EP_STRIDE 72    // E'    [160 n][64 px]
#define W_STRIDE  168   // E/w   [64 px][160 n] and clsWT [256 c][160 n]
#define CL_STRIDE 264   // cls   [160 n][256 c]
#define SL_STRIDE 72    // S_lds [160 n][64 px]
#define CT_STRIDE 264   // combT tile [80 n][256 k]

// kS2 LDS layout (bytes): 1 block/CU
#define S2_CLS  0        // [160][264] u16 = 84480
#define S2_FT   84480    // [64][264] u16 = 33792
#define S2_SL   118272   // [160][72] u16 = 23040
#define S2_LDS  141312

// kOut1 LDS layout (bytes)
#define O1_CLS  0        // [256][168] u16 = 86016
#define O1_E    86016    // [64][168] u16 = 21504
#define O1_LDS  107520

// workspace offsets (bytes); total 66,070,528 (same map as r8; rowP now smaller in-place)
#define WS_CLSF  0          // [8][160][256] f16
#define WS_CLSWT 655360     // [8][256][160] f16
#define WS_MP    1310720    // [8][16384] f32
#define WS_RZP   1835008    // [8][16384] f32
#define WS_MG    2359296    // [8][160] f32
#define WS_RZ    2364416    // [8][160] f32
#define WS_WCF   2369536    // [256][256] f16
#define WS_COMBT 2500608    // [8][160][256] f16
#define WS_ROWP  3155968    // [8][32][160][2] f32 = 327,680 (part aliases after kComb)
#define WS_PART  3155968    // [8][32][256][160] f16 (aliases ROWP; written later by kOut0)
#define WS_S     24127488   // [8][160][16384] f16

__device__ __forceinline__ u16 f2h(float f){ return __builtin_bit_cast(u16, (_Float16)f); }
__device__ __forceinline__ float h2f(u16 h){ return (float)__builtin_bit_cast(_Float16, h); }

// ---------------- k0: cls -> f16 (padded 160 rows, pads zero), clsWT = (cls @ Wf^T)^T f16
__global__ __launch_bounds__(256) void k0(const float* __restrict__ cls, const float* __restrict__ Wf,
                                          u16* __restrict__ clsF, u16* __restrict__ clsWT){
  int b = blockIdx.x / NPAD, n = blockIdx.x % NPAD, t = threadIdx.x;
  __shared__ float row[256];
  int bn = b*NPAD + n;
  if (n < NCLS){
    float v = cls[(b*NCLS + n)*CDIM + t];
    clsF[bn*CDIM + t] = f2h(v);
    row[t] = v;
    __syncthreads();
    float acc = 0.f;
    const float* wr = Wf + t*CDIM;
    #pragma unroll 4
    for (int c = 0; c < 256; c += 4){
      acc += row[c]*wr[c] + row[c+1]*wr[c+1] + row[c+2]*wr[c+2] + row[c+3]*wr[c+3];
    }
    clsWT[(b*CDIM + t)*NPAD + n] = f2h(acc);
  } else {
    clsF[bn*CDIM + t] = 0;
    clsWT[(b*CDIM + t)*NPAD + n] = 0;
  }
}

// ---------------- kW: Wc f32 -> f16
__global__ __launch_bounds__(512) void kW(const float* __restrict__ Wc, u16* __restrict__ WcF){
  int i = (blockIdx.x*512 + threadIdx.x)*4;
  f32x4 v = *(const f32x4*)&Wc[i];
  u16x4 o = {f2h(v[0]), f2h(v[1]), f2h(v[2]), f2h(v[3])};
  *(u16x4*)&WcF[i] = o;
}

// ---------------- kS2 v2: cls tile in LDS (kills serial L2 A-fragment chain, r8: VGPR=36,
// 40x ~440cy load->MFMA pairs). One block per (b, 512px chunk); 8 subtiles; stats from LDS S.
__global__ __launch_bounds__(512) void kS2(const float* __restrict__ feat, const u16* __restrict__ clsF,
                                           u16* __restrict__ Sg,
                                           float* __restrict__ mp, float* __restrict__ rzp,
                                           float* __restrict__ rowP){
  extern __shared__ char sm[];
  u16* clsL = (u16*)(sm + S2_CLS);
  u16* ftF  = (u16*)(sm + S2_FT);
  u16* Sl   = (u16*)(sm + S2_SL);
  int b = blockIdx.x & 7, ch = blockIdx.x >> 3, t = threadIdx.x;
  const float* featG = feat + (size_t)b*(CDIM*HW);
  const u16* clsB = clsF + b*NPAD*CDIM;
  u16* Sb = Sg + (size_t)b*NPAD*HW;
  // ---- stage cls [160][256] -> LDS [160][264] (once)
  #pragma unroll
  for (int it = 0; it < 10; ++it){
    int idx8 = (it*512 + t)*8;           // 40960 shorts exactly
    int n = idx8 >> 8, c = idx8 & 255;
    u16x8 v = *(const u16x8*)&clsB[idx8];
    *(u16x8*)&clsL[n*CL_STRIDE + c] = v;
  }
  int lane = t & 63, wv = t >> 6;
  int l15 = lane & 15, lk = (lane >> 4) & 3;
  int nh = wv >> 2, pq = wv & 3;
  int nbase = nh*80;
  int col = pq*16 + l15;
  float m_run = -3.0e38f, l_run = 0.f;   // live in t<160 threads (row = t)
  __syncthreads();

  for (int sub = 0; sub < 8; ++sub){
    int p0 = ch*512 + sub*64;
    // ---- stage feat tile f32 -> f16 LDS [64][264]
    {
      int p = t & 63, cg = t >> 6;
      #pragma unroll
      for (int i = 0; i < 8; ++i){
        int c0 = (i*8 + cg)*4;
        const float* g0 = featG + (size_t)c0*HW + p0 + p;
        float v0 = g0[0], v1 = g0[HW], v2 = g0[2*HW], v3 = g0[3*HW];
        u16x4 hv = {f2h(v0), f2h(v1), f2h(v2), f2h(v3)};
        *(u16x4*)&ftF[p*FT_STRIDE + c0] = hv;
      }
    }
    __syncthreads();   // B1: ftF ready (also orders prev-sub stats before this GEMM)
    // ---- GEMM fully LDS-fed
    f32x4 acc[5];
    #pragma unroll
    for (int f = 0; f < 5; ++f) acc[f] = (f32x4){0.f,0.f,0.f,0.f};
    #pragma unroll
    for (int kb = 0; kb < 8; ++kb){
      int ko = kb*32 + lk*8;
      f16x8 bh = *(const f16x8*)&ftF[(pq*16 + l15)*FT_STRIDE + ko];
      #pragma unroll
      for (int f = 0; f < 5; ++f){
        f16x8 ah = *(const f16x8*)&clsL[(nbase + f*16 + l15)*CL_STRIDE + ko];
        acc[f] = MFMA16F(ah, bh, acc[f], 0, 0, 0);
      }
    }
    // ---- write S: global (drains in background) + LDS copy for stats
    #pragma unroll
    for (int f = 0; f < 5; ++f){
      #pragma unroll
      for (int r = 0; r < 4; ++r){
        int n = nbase + 16*f + 4*lk + r;
        u16 h = f2h(acc[f][r]);
        Sb[(size_t)n*HW + p0 + col] = h;
        Sl[n*SL_STRIDE + col] = h;
      }
    }
    __syncthreads();   // B2: S_lds ready
    // ---- stats (t<160: rows; t>=448: pixels; middle threads run ahead to next stage)
    if (t < NPAD){
      float mt = -3.0e38f;
      #pragma unroll
      for (int q = 0; q < 8; ++q){
        u16x8 v = *(const u16x8*)&Sl[t*SL_STRIDE + q*8];
        #pragma unroll
        for (int j = 0; j < 8; ++j) mt = fmaxf(mt, h2f(v[j]));
      }
      float s0 = 0.f, s1 = 0.f;
      #pragma unroll
      for (int q = 0; q < 8; ++q){
        u16x8 v = *(const u16x8*)&Sl[t*SL_STRIDE + q*8];
        #pragma unroll
        for (int j = 0; j < 4; ++j){
          s0 += __expf(h2f(v[2*j]) - mt);
          s1 += __expf(h2f(v[2*j+1]) - mt);
        }
      }
      float st = s0 + s1;
      float m2 = fmaxf(m_run, mt);
      l_run = l_run*__expf(m_run - m2) + st*__expf(mt - m2);
      m_run = m2;
    } else if (t >= 448){
      int px = t - 448;
      float mt = -3.0e38f;
      for (int r = 0; r < NCLS; ++r) mt = fmaxf(mt, h2f(Sl[r*SL_STRIDE + px]));
      float s0 = 0.f, s1 = 0.f;
      for (int r = 0; r < NCLS; r += 2){
        s0 += __expf(h2f(Sl[r*SL_STRIDE + px]) - mt);
        if (r + 1 < NCLS) s1 += __expf(h2f(Sl[(r+1)*SL_STRIDE + px]) - mt);
      }
      mp[((size_t)b << 14) + p0 + px] = mt;
      rzp[((size_t)b << 14) + p0 + px] = 1.0f / (s0 + s1);
    }
  }
  if (t < NPAD){
    float* rp = rowP + ((size_t)(b*32 + ch)*NPAD + t)*2;
    rp[0] = m_run;
    rp[1] = l_run;
  }
}

// ---------------- kComb: reduce 32 row-partials -> m_g, rZ
__global__ __launch_bounds__(256) void kComb(const float* __restrict__ rowP,
                                             float* __restrict__ mg, float* __restrict__ rz){
  int b = blockIdx.x, t = threadIdx.x;
  if (t < NPAD){
    float m = -3.0e38f, l = 0.f;
    for (int s = 0; s < 32; ++s){
      const float* rp = rowP + ((size_t)(b*32 + s)*NPAD + t)*2;
      float ms = rp[0], ls = rp[1];
      float mn = fmaxf(m, ms);
      l = l*__expf(m - mn) + ls*__expf(ms - mn);
      m = mn;
    }
    mg[b*NPAD + t] = m;
    rz[b*NPAD + t] = 1.0f / l;
  }
}

// ---------------- kOut1 v2: clsWT in LDS, 8 subtiles per block
__global__ __launch_bounds__(512) void kOut1(const u16* __restrict__ Sg, const u16* __restrict__ clsWT,
                                             const float* __restrict__ mp, const float* __restrict__ rzp,
                                             const float* __restrict__ feat, float* __restrict__ out1){
  extern __shared__ char sm[];
  u16* A = (u16*)(sm + O1_CLS);   // [256 c][168 n]
  u16* E = (u16*)(sm + O1_E);     // [64 px][168 n]
  int b = blockIdx.x & 7, ch = blockIdx.x >> 3, t = threadIdx.x;
  const u16* Sb = Sg + (size_t)b*NPAD*HW;
  const u16* clsWB = clsWT + b*CDIM*NPAD;
  const float* featB = feat + (size_t)b*CDIM*HW;
  // ---- stage clsWT [256][160] -> LDS [256][168] (once)
  #pragma unroll
  for (int it = 0; it < 10; ++it){
    int idx8 = (it*512 + t)*8;           // 40960 shorts exactly
    int c = idx8 / NPAD, n = idx8 % NPAD;
    u16x8 v = *(const u16x8*)&clsWB[idx8];
    *(u16x8*)&A[c*W_STRIDE + n] = v;
  }
  int lane = t & 63, wv = t >> 6;
  int l15 = lane & 15, lk = (lane >> 4) & 3;
  int cstrip = wv*32;
  int rr = t >> 3, px8 = (t & 7)*8;
  __syncthreads();

  for (int sub = 0; sub < 8; ++sub){
    int p0 = ch*512 + sub*64;
    const float* mpB = mp + ((size_t)b << 14) + p0;
    const float* rzB = rzp + ((size_t)b << 14) + p0;
    // ---- E tile: E[px][n] = exp(S - mp[px]) (0 for pad n)
    #pragma unroll
    for (int ps = 0; ps < 3; ++ps){
      int rowi = ps*64 + rr;
      if (rowi < NPAD){
        float ev[8];
        if (rowi < NCLS){
          u16x8 v = *(const u16x8*)&Sb[(size_t)rowi*HW + p0 + px8];
          #pragma unroll
          for (int j = 0; j < 8; ++j) ev[j] = __expf(h2f(v[j]) - mpB[px8 + j]);
        } else {
          #pragma unroll
          for (int j = 0; j < 8; ++j) ev[j] = 0.f;
        }
        #pragma unroll
        for (int j = 0; j < 8; ++j) E[(px8 + j)*W_STRIDE + rowi] = f2h(ev[j]);
      }
    }
    __syncthreads();   // E ready
    // ---- GEMM (A and B both LDS) + epilogue
    f32x4 acc[2][4];
    #pragma unroll
    for (int cf = 0; cf < 2; ++cf)
      #pragma unroll
      for (int pf = 0; pf < 4; ++pf) acc[cf][pf] = (f32x4){0.f,0.f,0.f,0.f};
    #pragma unroll
    for (int kb = 0; kb < 5; ++kb){
      int ko = kb*32 + lk*8;
      f16x8 a0 = *(const f16x8*)&A[(cstrip + l15)*W_STRIDE + ko];
      f16x8 a1 = *(const f16x8*)&A[(cstrip + 16 + l15)*W_STRIDE + ko];
      #pragma unroll
      for (int pf = 0; pf < 4; ++pf){
        f16x8 bb = *(const f16x8*)&E[(pf*16 + l15)*W_STRIDE + ko];
        acc[0][pf] = MFMA16F(a0, bb, acc[0][pf], 0, 0, 0);
        acc[1][pf] = MFMA16F(a1, bb, acc[1][pf], 0, 0, 0);
      }
    }
    #pragma unroll
    for (int cf = 0; cf < 2; ++cf){
      #pragma unroll
      for (int r = 0; r < 4; ++r){
        int c = cstrip + cf*16 + lk*4 + r;
        const float* fr = featB + (size_t)c*HW + p0;
        float* ob = out1 + (size_t)(b*CDIM + c)*HW + p0;
        #pragma unroll
        for (int pf = 0; pf < 4; ++pf){
          int pp = pf*16 + l15;
          ob[pp] = acc[cf][pf][r]*rzB[pp] + fr[pp];
        }
      }
    }
    __syncthreads();   // GEMM reads done before next E overwrite
  }
}

// ---------------- kOut0: part[c][n] = sum_p featF16[c][p] * exp(S - m_g[n])  (512 px/block)
__global__ __launch_bounds__(512) void kOut0(const u16* __restrict__ Sg, const float* __restrict__ feat,
                                             const float* __restrict__ mg, u16* __restrict__ part){
  extern __shared__ char sm[];
  u16* Ep = (u16*)sm;                        // [NPAD][EP_STRIDE]
  u16* fN = (u16*)(sm + NPAD*EP_STRIDE*2);   // [CDIM][FN_STRIDE]
  int b = blockIdx.x & 7, pr = blockIdx.x >> 3, t = threadIdx.x;
  const u16* Sb = Sg + (size_t)b*NPAD*HW;
  const float* featB = feat + (size_t)b*CDIM*HW;
  const float* mgB = mg + b*NPAD;
  int lane = t & 63, wv = t >> 6;
  int l15 = lane & 15, lk = (lane >> 4) & 3;
  int cstrip = wv*32;
  int rr = t >> 3, px8 = (t & 7)*8;
  f32x4 acc[2][10];
  #pragma unroll
  for (int cf = 0; cf < 2; ++cf)
    #pragma unroll
    for (int nf = 0; nf < 10; ++nf) acc[cf][nf] = (f32x4){0.f,0.f,0.f,0.f};
  for (int ck = 0; ck < 8; ++ck){
    int p0 = pr*512 + ck*64;
    #pragma unroll
    for (int ps = 0; ps < 3; ++ps){
      int rowi = ps*64 + rr;
      if (rowi < NPAD){
        u16x8 v = *(const u16x8*)&Sb[(size_t)rowi*HW + p0 + px8];
        float m = mgB[rowi];
        u16x8 o;
        #pragma unroll
        for (int j = 0; j < 8; ++j) o[j] = f2h(__expf(h2f(v[j]) - m));
        *(u16x8*)&Ep[rowi*EP_STRIDE + px8] = o;
      }
    }
    #pragma unroll
    for (int ps = 0; ps < 4; ++ps){
      int c = ps*64 + rr;
      const float* g = featB + (size_t)c*HW + p0 + px8;
      f32x4 v0 = *(const f32x4*)&g[0];
      f32x4 v1 = *(const f32x4*)&g[4];
      u16x8 o = {f2h(v0[0]), f2h(v0[1]), f2h(v0[2]), f2h(v0[3]),
                 f2h(v1[0]), f2h(v1[1]), f2h(v1[2]), f2h(v1[3])};
      *(u16x8*)&fN[c*FN_STRIDE + px8] = o;
    }
    __syncthreads();
    #pragma unroll
    for (int kb = 0; kb < 2; ++kb){
      int ko = kb*32 + lk*8;
      f16x8 a0 = *(const f16x8*)&fN[(cstrip + l15)*FN_STRIDE + ko];
      f16x8 a1 = *(const f16x8*)&fN[(cstrip + 16 + l15)*FN_STRIDE + ko];
      #pragma unroll
      for (int nf = 0; nf < 10; ++nf){
        f16x8 bb = *(const f16x8*)&Ep[(nf*16 + l15)*EP_STRIDE + ko];
        acc[0][nf] = MFMA16F(a0, bb, acc[0][nf], 0, 0, 0);
        acc[1][nf] = MFMA16F(a1, bb, acc[1][nf], 0, 0, 0);
      }
    }
    __syncthreads();
  }
  #pragma unroll
  for (int cf = 0; cf < 2; ++cf){
    #pragma unroll
    for (int nf = 0; nf < 10; ++nf){
      #pragma unroll
      for (int r = 0; r < 4; ++r){
        int c = cstrip + cf*16 + lk*4 + r;
        int n = nf*16 + l15;
        part[((size_t)(b*32 + pr)*CDIM + c)*NPAD + n] = f2h(acc[cf][nf][r]);
      }
    }
  }
}

// ---------------- k4a: streaming reduce of part over 32 chunks, fold rZ -> combT[b][n][c] f16
__global__ __launch_bounds__(256) void k4a(const u16* __restrict__ part, const float* __restrict__ rz,
                                           u16* __restrict__ combT){
  int b = blockIdx.x / 20, sub = blockIdx.x % 20, t = threadIdx.x;
  int idx8 = (sub*256 + t)*8;
  int c = idx8 / NPAD, n0 = idx8 % NPAD;
  const u16* base = part + (size_t)(b*32)*CDIM*NPAD + idx8;
  float a[8];
  #pragma unroll
  for (int j = 0; j < 8; ++j) a[j] = 0.f;
  for (int s = 0; s < 32; ++s){
    u16x8 v = *(const u16x8*)&base[(size_t)s*CDIM*NPAD];
    #pragma unroll
    for (int j = 0; j < 8; ++j) a[j] += h2f(v[j]);
  }
  const float* rzB = rz + b*NPAD + n0;
  #pragma unroll
  for (int j = 0; j < 8; ++j){
    combT[((size_t)(b*NPAD) + n0 + j)*CDIM + c] = f2h(a[j] * rzB[j]);
  }
}

// ---------------- k4b: out0[n][c] = cls + combT[n][:] @ WcF[c][:]  (MFMA, 80 n-rows/block)
__global__ __launch_bounds__(512) void k4b(const u16* __restrict__ combT, const u16* __restrict__ WcF,
                                           const float* __restrict__ cls, float* __restrict__ out0){
  extern __shared__ char sm[];
  u16* A = (u16*)sm;   // [80][CT_STRIDE]
  int b = blockIdx.x >> 1, nb = blockIdx.x & 1, t = threadIdx.x;
  const u16* cb = combT + (size_t)(b*NPAD + nb*80)*CDIM;
  #pragma unroll
  for (int it = 0; it < 10; ++it){
    int idx8 = (it*512 + t)*8;
    if (idx8 < 80*256){
      int row = idx8 >> 8, k0 = idx8 & 255;
      u16x8 v = *(const u16x8*)&cb[idx8];
      *(u16x8*)&A[row*CT_STRIDE + k0] = v;
    }
  }
  __syncthreads();
  int lane = t & 63, wv = t >> 6;
  int l15 = lane & 15, lk = (lane >> 4) & 3;
  int cstrip = wv*32;
  f32x4 acc[5][2];
  #pragma unroll
  for (int f = 0; f < 5; ++f)
    #pragma unroll
    for (int ct = 0; ct < 2; ++ct) acc[f][ct] = (f32x4){0.f,0.f,0.f,0.f};
  #pragma unroll
  for (int kb = 0; kb < 8; ++kb){
    int ko = kb*32 + lk*8;
    f16x8 b0 = *(const f16x8*)&WcF[(cstrip + l15)*CDIM + ko];
    f16x8 b1 = *(const f16x8*)&WcF[(cstrip + 16 + l15)*CDIM + ko];
    #pragma unroll
    for (int f = 0; f < 5; ++f){
      f16x8 af = *(const f16x8*)&A[(f*16 + l15)*CT_STRIDE + ko];
      acc[f][0] = MFMA16F(af, b0, acc[f][0], 0, 0, 0);
      acc[f][1] = MFMA16F(af, b1, acc[f][1], 0, 0, 0);
    }
  }
  #pragma unroll
  for (int f = 0; f < 5; ++f){
    #pragma unroll
    for (int r = 0; r < 4; ++r){
      int n = nb*80 + f*16 + lk*4 + r;
      if (n < NCLS){
        #pragma unroll
        for (int ct = 0; ct < 2; ++ct){
          int c = cstrip + ct*16 + l15;
          out0[(size_t)(b*NCLS + n)*CDIM + c] = cls[(size_t)(b*NCLS + n)*CDIM + c] + acc[f][ct][r];
        }
      }
    }
  }
}

extern "C" void kernel_launch(void* const* d_in, const int* in_sizes, int n_in,
                              void* d_out, int out_size, void* d_ws, size_t ws_size,
                              hipStream_t stream){
  (void)in_sizes; (void)n_in; (void)out_size; (void)ws_size;
  const float* cls  = (const float*)d_in[0];   // [8][150][256]
  const float* feat = (const float*)d_in[1];   // [8][256][16384]
  const float* Wc   = (const float*)d_in[2];   // [256][256]
  const float* Wf   = (const float*)d_in[3];   // [256][256]
  float* out0 = (float*)d_out;                 // [8][150][256]
  float* out1 = out0 + 8*NCLS*CDIM;            // [8][256][16384]
  char* ws = (char*)d_ws;
  u16*   clsF   = (u16*)(ws + WS_CLSF);
  u16*   clsWT  = (u16*)(ws + WS_CLSWT);
  float* mpv    = (float*)(ws + WS_MP);
  float* rzpv   = (float*)(ws + WS_RZP);
  float* mgv    = (float*)(ws + WS_MG);
  float* rzv    = (float*)(ws + WS_RZ);
  u16*   WcFv   = (u16*)(ws + WS_WCF);
  u16*   combTv = (u16*)(ws + WS_COMBT);
  float* rowPv  = (float*)(ws + WS_ROWP);
  u16*   partv  = (u16*)(ws + WS_PART);
  u16*   Sgp    = (u16*)(ws + WS_S);

  hipFuncSetAttribute((const void*)kS2,  hipFuncAttributeMaxDynamicSharedMemorySize, S2_LDS);
  hipFuncSetAttribute((const void*)kOut1, hipFuncAttributeMaxDynamicSharedMemorySize, O1_LDS);

  k0   <<<8*NPAD, 256, 0, stream>>>(cls, Wf, clsF, clsWT);
  kW   <<<32, 512, 0, stream>>>(Wc, WcFv);
  kS2  <<<256, 512, S2_LDS, stream>>>(feat, clsF, Sgp, mpv, rzpv, rowPv);
  kComb<<<8, 256, 0, stream>>>(rowPv, mgv, rzv);
  kOut1<<<256, 512, O1_LDS, stream>>>(Sgp, clsWT, mpv, rzpv, feat, out1);
  kOut0<<<256, 512, (NPAD*EP_STRIDE + CDIM*FN_STRIDE)*2, stream>>>(Sgp, feat, mgv, partv);
  k4a  <<<160, 256, 0, stream>>>(partv, rzv, combTv);
  k4b  <<<16, 512, 80*CT_STRIDE*2, stream>>>(combTv, WcFv, cls, out0);
}